// Round 1
// baseline (28624.008 us; speedup 1.0000x reference)
//
#include <hip/hip_runtime.h>

#define B_ 64
#define T_ 256
#define F_ 512
#define H_ 1024
#define O_ 512
#define G3_ 3072

#define OUT_N   (T_ * B_ * O_)        /* 8388608 */
#define NSEL_IX OUT_N
#define SEL_OFF (OUT_N + 1)

// ---------------- device state (rewritten every call before use) ----------------
__device__ double g_WihT[(size_t)F_ * G3_];    // [k][col]  12.6 MB
__device__ double g_WhhT[(size_t)H_ * G3_];    // [k][col]  25.2 MB
__device__ double g_WselT[(size_t)H_ * F_];    // [k][f]     4.2 MB
__device__ double g_bih[G3_];
__device__ double g_bhh[G3_];
__device__ double g_bsel[F_];
__device__ double g_h64[B_ * H_];              // current hidden (f64)
__device__ double g_ci64[B_ * F_];             // current masked input (f64)
__device__ double g_part[16ull * 4 * B_ * H_]; // [ks][ch][b][j] split-K partials, 33.5 MB
__device__ float  g_hist[(size_t)T_ * B_ * H_];// h history (f32) for batched out-GEMM, 67 MB
__device__ unsigned int g_selcnt;

// ---------------- prep: weight transposes to f64 ----------------
__global__ void k_prep_wihT(const float* __restrict__ W) {
  int i = blockIdx.x * 256 + threadIdx.x;
  if (i < F_ * G3_) {
    int k = i / G3_, c = i % G3_;
    g_WihT[i] = (double)W[(size_t)c * F_ + k];
  }
}
__global__ void k_prep_whhT(const float* __restrict__ W) {
  int i = blockIdx.x * 256 + threadIdx.x;
  if (i < H_ * G3_) {
    int k = i / G3_, c = i % G3_;
    g_WhhT[i] = (double)W[(size_t)c * H_ + k];
  }
}
__global__ void k_prep_wselT(const float* __restrict__ W) {
  int i = blockIdx.x * 256 + threadIdx.x;
  if (i < H_ * F_) {
    int k = i / F_, f = i % F_;
    g_WselT[i] = (double)W[(size_t)f * H_ + k];
  }
}
__global__ void k_prep_misc(const float* __restrict__ x,
                            const float* __restrict__ bih,
                            const float* __restrict__ bhh,
                            const float* __restrict__ bsel,
                            float* __restrict__ out) {
  int i = blockIdx.x * 256 + threadIdx.x;   // grid 256x256 -> 65536
  if (i < B_ * H_) g_h64[i] = 0.0;
  if (i < B_ * F_) {
    int b = i >> 9, f = i & 511;
    g_ci64[i] = (double)x[(size_t)b * (T_ * F_) + f];  // t=0: curr_in = x_0
    out[(size_t)SEL_OFF + i] = 1.0f;                   // sel_weights[0] = ones
  }
  if (i < G3_) { g_bih[i] = (double)bih[i]; g_bhh[i] = (double)bhh[i]; }
  if (i < F_)  g_bsel[i] = (double)bsel[i];
  if (i == 0)  g_selcnt = 0u;
}

// ---------------- per-step: gates partial GEMM (f64, split-K x16) ----------------
// grid: (32 jc, 16 ks), block 512.  thread: j = jc*32 + (tid&31), b0 = (tid>>5)*4
__global__ __launch_bounds__(512) void k_gates() {
  const int tid = threadIdx.x;
  const int jc  = blockIdx.x;
  const int ks  = blockIdx.y;
  const int jl  = tid & 31;
  const int bq  = tid >> 5;
  const int b0  = bq << 2;
  const int j   = (jc << 5) + jl;

  __shared__ double s[32 * 64];   // [kl][b], 16 KB

  double ar0=0,ar1=0,ar2=0,ar3=0;
  double az0=0,az1=0,az2=0,az3=0;
  double ai0=0,ai1=0,ai2=0,ai3=0;   // i_n (input-side) partial
  double ah0=0,ah1=0,ah2=0,ah3=0;   // h_n (hidden-side) partial

  // ---- phase A: gi over curr_in, k in [ks*32, ks*32+32)
  {
    const int kbase = ks * 32;
    #pragma unroll
    for (int it = 0; it < 4; ++it) {
      int e  = it * 512 + tid;       // 0..2047
      int bb = e & 63;
      int kl = e >> 6;               // 0..31
      s[kl * 64 + bb] = g_ci64[bb * F_ + kbase + kl];
    }
    __syncthreads();
    const double* wp = &g_WihT[(size_t)kbase * G3_ + j];
    #pragma unroll 4
    for (int kl = 0; kl < 32; ++kl) {
      double wr = wp[0];
      double wz = wp[H_];
      double wn = wp[2 * H_];
      const double2* sp = (const double2*)&s[kl * 64 + b0];
      double2 a01 = sp[0], a23 = sp[1];
      ar0 = fma(a01.x, wr, ar0); az0 = fma(a01.x, wz, az0); ai0 = fma(a01.x, wn, ai0);
      ar1 = fma(a01.y, wr, ar1); az1 = fma(a01.y, wz, az1); ai1 = fma(a01.y, wn, ai1);
      ar2 = fma(a23.x, wr, ar2); az2 = fma(a23.x, wz, az2); ai2 = fma(a23.x, wn, ai2);
      ar3 = fma(a23.y, wr, ar3); az3 = fma(a23.y, wz, az3); ai3 = fma(a23.y, wn, ai3);
      wp += G3_;
    }
    __syncthreads();
  }

  // ---- phase B: gh over h, k in [ks*64, ks*64+64), two tiles of 32
  #pragma unroll 1
  for (int kt = 0; kt < 2; ++kt) {
    const int kbase = ks * 64 + kt * 32;
    #pragma unroll
    for (int it = 0; it < 4; ++it) {
      int e  = it * 512 + tid;
      int bb = e & 63;
      int kl = e >> 6;
      s[kl * 64 + bb] = g_h64[bb * H_ + kbase + kl];
    }
    __syncthreads();
    const double* wp = &g_WhhT[(size_t)kbase * G3_ + j];
    #pragma unroll 4
    for (int kl = 0; kl < 32; ++kl) {
      double wr = wp[0];
      double wz = wp[H_];
      double wn = wp[2 * H_];
      const double2* sp = (const double2*)&s[kl * 64 + b0];
      double2 a01 = sp[0], a23 = sp[1];
      ar0 = fma(a01.x, wr, ar0); az0 = fma(a01.x, wz, az0); ah0 = fma(a01.x, wn, ah0);
      ar1 = fma(a01.y, wr, ar1); az1 = fma(a01.y, wz, az1); ah1 = fma(a01.y, wn, ah1);
      ar2 = fma(a23.x, wr, ar2); az2 = fma(a23.x, wz, az2); ah2 = fma(a23.x, wn, ah2);
      ar3 = fma(a23.y, wr, ar3); az3 = fma(a23.y, wz, az3); ah3 = fma(a23.y, wn, ah3);
      wp += G3_;
    }
    __syncthreads();
  }

  // ---- write partials: g_part[ks][ch][b][j]
  const size_t chs  = (size_t)B_ * H_;                       // 65536
  size_t base = (size_t)ks * 4 * chs + (size_t)b0 * H_ + j;
  g_part[base + 0*H_]           = ar0;
  g_part[base + 1*H_]           = ar1;
  g_part[base + 2*H_]           = ar2;
  g_part[base + 3*H_]           = ar3;
  g_part[base + chs + 0*H_]     = az0;
  g_part[base + chs + 1*H_]     = az1;
  g_part[base + chs + 2*H_]     = az2;
  g_part[base + chs + 3*H_]     = az3;
  g_part[base + 2*chs + 0*H_]   = ai0;
  g_part[base + 2*chs + 1*H_]   = ai1;
  g_part[base + 2*chs + 2*H_]   = ai2;
  g_part[base + 2*chs + 3*H_]   = ai3;
  g_part[base + 3*chs + 0*H_]   = ah0;
  g_part[base + 3*chs + 1*H_]   = ah1;
  g_part[base + 3*chs + 2*H_]   = ah2;
  g_part[base + 3*chs + 3*H_]   = ah3;
}

// ---------------- per-step: pointwise GRU update ----------------
__global__ __launch_bounds__(256) void k_hupdate(int t) {
  int i = blockIdx.x * 256 + threadIdx.x;    // grid 256 -> 65536
  int jj = i & 1023;
  const size_t chs = (size_t)B_ * H_;
  double sr = 0.0, sz = 0.0, si = 0.0, sh = 0.0;
  #pragma unroll 4
  for (int ks = 0; ks < 16; ++ks) {
    size_t base = (size_t)ks * 4 * chs + i;
    sr += g_part[base];
    sz += g_part[base + chs];
    si += g_part[base + 2 * chs];
    sh += g_part[base + 3 * chs];
  }
  sr += g_bih[jj] + g_bhh[jj];
  sz += g_bih[H_ + jj] + g_bhh[H_ + jj];
  si += g_bih[2 * H_ + jj];
  sh += g_bhh[2 * H_ + jj];
  double r = 1.0 / (1.0 + exp(-sr));
  double z = 1.0 / (1.0 + exp(-sz));
  double n = tanh(si + r * sh);
  double hold = g_h64[i];
  double hnew = (1.0 - z) * n + z * hold;
  g_h64[i] = hnew;
  g_hist[(size_t)t * chs + i] = (float)hnew;
}

// ---------------- per-step: logits (f64) + Bernoulli mask + next curr_in ----------------
// grid: (32 fc, 8 bg), block 256. thread: kh=tid&1, f=fc*16+((tid>>1)&15), b=bg*8+(tid>>5)
__global__ __launch_bounds__(256) void k_logitmask(int t,
                                                   const float* __restrict__ u,
                                                   const float* __restrict__ x,
                                                   float* __restrict__ out) {
  const int tid = threadIdx.x;
  const int kh  = tid & 1;
  const int fl  = (tid >> 1) & 15;
  const int bl  = tid >> 5;
  const int f   = blockIdx.x * 16 + fl;
  const int b   = blockIdx.y * 8 + bl;

  const double* hrow = &g_h64[(size_t)b * H_ + kh * 512];
  const double* wcol = &g_WselT[(size_t)(kh * 512) * F_ + f];
  double acc = 0.0;
  #pragma unroll 4
  for (int kk = 0; kk < 512; ++kk) {
    acc = fma(hrow[kk], wcol[0], acc);
    wcol += F_;
  }
  double other = __shfl_xor(acc, 1, 64);
  acc += other;

  bool wflag = false;
  if (kh == 0) {
    double logit = acc + g_bsel[f];
    double sig = 1.0 / (1.0 + exp(-logit));
    int tp = t + 1;
    float uv = u[(size_t)tp * (B_ * F_) + b * F_ + f];
    wflag = sig > (double)uv;
    out[(size_t)SEL_OFF + (size_t)tp * (B_ * F_) + b * F_ + f] = wflag ? 1.0f : 0.0f;
    g_ci64[b * F_ + f] = wflag ? (double)x[(size_t)b * (T_ * F_) + (size_t)tp * F_ + f] : 0.0;
  }
  unsigned long long bal = __ballot(wflag);
  if ((tid & 63) == 0) atomicAdd(&g_selcnt, (unsigned)__popcll(bal));
}

// ---------------- batched out-GEMM (f32): out[m][o] = hist[m][:] . W_out[o][:] + b_out ----------------
// M = T*B = 16384, N = O = 512, K = H = 1024. grid (8, 256), block 256, 64x64 tiles, 4x4 micro.
__global__ __launch_bounds__(256) void k_out(const float* __restrict__ Wo,
                                             const float* __restrict__ bo,
                                             float* __restrict__ out) {
  __shared__ float sA[32][68];
  __shared__ float sB[32][68];
  const int tid = threadIdx.x;
  const int to = tid & 15, tm = tid >> 4;
  const int m0 = blockIdx.y * 64, o0 = blockIdx.x * 64;
  float acc[4][4] = {{0.f}};
  for (int kt = 0; kt < 1024 / 32; ++kt) {
    #pragma unroll
    for (int it = 0; it < 8; ++it) {
      int e  = it * 256 + tid;   // 0..2047
      int rl = e >> 5;           // 0..63
      int kl = e & 31;
      sA[kl][rl] = g_hist[(size_t)(m0 + rl) * H_ + kt * 32 + kl];
      sB[kl][rl] = Wo[(size_t)(o0 + rl) * H_ + kt * 32 + kl];
    }
    __syncthreads();
    #pragma unroll
    for (int kl = 0; kl < 32; ++kl) {
      float a[4], bv[4];
      #pragma unroll
      for (int i = 0; i < 4; ++i) a[i] = sA[kl][tm * 4 + i];
      #pragma unroll
      for (int i = 0; i < 4; ++i) bv[i] = sB[kl][to * 4 + i];
      #pragma unroll
      for (int i = 0; i < 4; ++i)
        #pragma unroll
        for (int c = 0; c < 4; ++c)
          acc[i][c] = fmaf(a[i], bv[c], acc[i][c]);
    }
    __syncthreads();
  }
  #pragma unroll
  for (int i = 0; i < 4; ++i) {
    int m = m0 + tm * 4 + i;
    #pragma unroll
    for (int c = 0; c < 4; ++c) {
      int o = o0 + to * 4 + c;
      out[(size_t)m * O_ + o] = acc[i][c] + bo[o];
    }
  }
}

__global__ void k_finalize(float* __restrict__ out) {
  if (blockIdx.x == 0 && threadIdx.x == 0) out[NSEL_IX] = (float)g_selcnt;
}

// ---------------- launcher ----------------
extern "C" void kernel_launch(void* const* d_in, const int* in_sizes, int n_in,
                              void* d_out, int out_size, void* d_ws, size_t ws_size,
                              hipStream_t stream) {
  (void)in_sizes; (void)n_in; (void)out_size; (void)d_ws; (void)ws_size;
  const float* x     = (const float*)d_in[0];
  const float* u     = (const float*)d_in[1];
  const float* W_ih  = (const float*)d_in[2];
  const float* b_ih  = (const float*)d_in[3];
  const float* W_hh  = (const float*)d_in[4];
  const float* b_hh  = (const float*)d_in[5];
  const float* W_out = (const float*)d_in[6];
  const float* b_out = (const float*)d_in[7];
  const float* W_sel = (const float*)d_in[8];
  const float* b_sel = (const float*)d_in[9];
  float* out = (float*)d_out;

  k_prep_wihT <<<(F_ * G3_ + 255) / 256, 256, 0, stream>>>(W_ih);
  k_prep_whhT <<<(H_ * G3_ + 255) / 256, 256, 0, stream>>>(W_hh);
  k_prep_wselT<<<(H_ * F_ + 255) / 256, 256, 0, stream>>>(W_sel);
  k_prep_misc <<<256, 256, 0, stream>>>(x, b_ih, b_hh, b_sel, out);

  for (int t = 0; t < T_; ++t) {
    k_gates  <<<dim3(32, 16), 512, 0, stream>>>();
    k_hupdate<<<256, 256, 0, stream>>>(t);
    if (t < T_ - 1)
      k_logitmask<<<dim3(32, 8), 256, 0, stream>>>(t, u, x, out);
  }

  k_out<<<dim3(8, 256), 256, 0, stream>>>(W_out, b_out, out);
  k_finalize<<<1, 1, 0, stream>>>(out);
}

// Round 2
// 14739.577 us; speedup vs baseline: 1.9420x; 1.9420x over previous
//
#include <hip/hip_runtime.h>

#define B_ 64
#define T_ 256
#define F_ 512
#define H_ 1024
#define O_ 512
#define G3_ 3072
#define KS_ 8

#define OUT_N   (T_ * B_ * O_)        /* 8388608 */
#define NSEL_IX OUT_N
#define SEL_OFF (OUT_N + 1)

// ---------------- device state (rewritten every call before use) ----------------
__device__ float  g_WihTf[(size_t)F_ * G3_];    // [k][col]  6.3 MB
__device__ float  g_WhhTf[(size_t)H_ * G3_];    // [k][col] 12.6 MB
__device__ float  g_WselTf[(size_t)H_ * F_];    // [k][f]    2.1 MB
__device__ double g_bih[G3_];
__device__ double g_bhh[G3_];
__device__ double g_bsel[F_];
__device__ double g_h64[B_ * H_];               // current hidden (f64)
__device__ double g_ci64[B_ * F_];              // current masked input (f64)
__device__ double g_part[(size_t)KS_ * 4 * B_ * H_]; // [ks][ch][b][j] split-K partials, 16.8 MB
__device__ float  g_hist[(size_t)T_ * B_ * H_]; // h history (f32) for batched out-GEMM, 67 MB
__device__ unsigned int g_selcnt;

// ---------------- prep: weight transposes to f32 [k][col] ----------------
__global__ void k_prep_wihT(const float* __restrict__ W) {
  int i = blockIdx.x * 256 + threadIdx.x;
  if (i < F_ * G3_) {
    int k = i / G3_, c = i % G3_;
    g_WihTf[i] = W[(size_t)c * F_ + k];
  }
}
__global__ void k_prep_whhT(const float* __restrict__ W) {
  int i = blockIdx.x * 256 + threadIdx.x;
  if (i < H_ * G3_) {
    int k = i / G3_, c = i % G3_;
    g_WhhTf[i] = W[(size_t)c * H_ + k];
  }
}
__global__ void k_prep_wselT(const float* __restrict__ W) {
  int i = blockIdx.x * 256 + threadIdx.x;
  if (i < H_ * F_) {
    int k = i / F_, f = i % F_;
    g_WselTf[i] = W[(size_t)f * H_ + k];
  }
}
__global__ void k_prep_misc(const float* __restrict__ x,
                            const float* __restrict__ bih,
                            const float* __restrict__ bhh,
                            const float* __restrict__ bsel,
                            float* __restrict__ out) {
  int i = blockIdx.x * 256 + threadIdx.x;   // grid 256x256 -> 65536
  if (i < B_ * H_) g_h64[i] = 0.0;
  if (i < B_ * F_) {
    int b = i >> 9, f = i & 511;
    g_ci64[i] = (double)x[(size_t)b * (T_ * F_) + f];  // t=0: curr_in = x_0
    out[(size_t)SEL_OFF + i] = 1.0f;                   // sel_weights[0] = ones
  }
  if (i < G3_) { g_bih[i] = (double)bih[i]; g_bhh[i] = (double)bhh[i]; }
  if (i < F_)  g_bsel[i] = (double)bsel[i];
  if (i == 0)  g_selcnt = 0u;
}

// ---------------- per-step: gates partial GEMM (f64 acc, f32 weights, split-K x8) ----------------
// grid: (32 jc, 8 ks), block 512.  thread: j = jc*32 + (tid&31), b0 = (tid>>5)*4
__global__ __launch_bounds__(512) void k_gates() {
  const int tid = threadIdx.x;
  const int jc  = blockIdx.x;
  const int ks  = blockIdx.y;
  const int jl  = tid & 31;
  const int bq  = tid >> 5;
  const int b0  = bq << 2;
  const int j   = (jc << 5) + jl;

  __shared__ double s[32 * 66];   // [kl][b] pad->66 keeps double2 16B-aligned, 16.9 KB

  double ar0=0,ar1=0,ar2=0,ar3=0;
  double az0=0,az1=0,az2=0,az3=0;
  double ai0=0,ai1=0,ai2=0,ai3=0;   // i_n (input-side) partial
  double ah0=0,ah1=0,ah2=0,ah3=0;   // h_n (hidden-side) partial

  // ---- phase A: gi over curr_in, k in [ks*64, ks*64+64), two 32-tiles
  #pragma unroll 1
  for (int kt = 0; kt < 2; ++kt) {
    const int kbase = ks * 64 + kt * 32;
    #pragma unroll
    for (int it = 0; it < 4; ++it) {
      int e  = it * 512 + tid;       // 0..2047
      int kl = e & 31;               // consecutive lanes -> consecutive k (coalesced)
      int bb = e >> 5;               // 0..63
      s[kl * 66 + bb] = g_ci64[bb * F_ + kbase + kl];
    }
    __syncthreads();
    const float* wp = &g_WihTf[(size_t)kbase * G3_ + j];
    #pragma unroll 4
    for (int kl = 0; kl < 32; ++kl) {
      double wr = (double)wp[0];
      double wz = (double)wp[H_];
      double wn = (double)wp[2 * H_];
      const double2* sp = (const double2*)&s[kl * 66 + b0];
      double2 a01 = sp[0], a23 = sp[1];
      ar0 = fma(a01.x, wr, ar0); az0 = fma(a01.x, wz, az0); ai0 = fma(a01.x, wn, ai0);
      ar1 = fma(a01.y, wr, ar1); az1 = fma(a01.y, wz, az1); ai1 = fma(a01.y, wn, ai1);
      ar2 = fma(a23.x, wr, ar2); az2 = fma(a23.x, wz, az2); ai2 = fma(a23.x, wn, ai2);
      ar3 = fma(a23.y, wr, ar3); az3 = fma(a23.y, wz, az3); ai3 = fma(a23.y, wn, ai3);
      wp += G3_;
    }
    __syncthreads();
  }

  // ---- phase B: gh over h, k in [ks*128, ks*128+128), four 32-tiles
  #pragma unroll 1
  for (int kt = 0; kt < 4; ++kt) {
    const int kbase = ks * 128 + kt * 32;
    #pragma unroll
    for (int it = 0; it < 4; ++it) {
      int e  = it * 512 + tid;
      int kl = e & 31;
      int bb = e >> 5;
      s[kl * 66 + bb] = g_h64[bb * H_ + kbase + kl];
    }
    __syncthreads();
    const float* wp = &g_WhhTf[(size_t)kbase * G3_ + j];
    #pragma unroll 4
    for (int kl = 0; kl < 32; ++kl) {
      double wr = (double)wp[0];
      double wz = (double)wp[H_];
      double wn = (double)wp[2 * H_];
      const double2* sp = (const double2*)&s[kl * 66 + b0];
      double2 a01 = sp[0], a23 = sp[1];
      ar0 = fma(a01.x, wr, ar0); az0 = fma(a01.x, wz, az0); ah0 = fma(a01.x, wn, ah0);
      ar1 = fma(a01.y, wr, ar1); az1 = fma(a01.y, wz, az1); ah1 = fma(a01.y, wn, ah1);
      ar2 = fma(a23.x, wr, ar2); az2 = fma(a23.x, wz, az2); ah2 = fma(a23.x, wn, ah2);
      ar3 = fma(a23.y, wr, ar3); az3 = fma(a23.y, wz, az3); ah3 = fma(a23.y, wn, ah3);
      wp += G3_;
    }
    __syncthreads();
  }

  // ---- write partials: g_part[ks][ch][b][j]
  const size_t chs  = (size_t)B_ * H_;                       // 65536
  size_t base = (size_t)ks * 4 * chs + (size_t)b0 * H_ + j;
  g_part[base + 0*H_]           = ar0;
  g_part[base + 1*H_]           = ar1;
  g_part[base + 2*H_]           = ar2;
  g_part[base + 3*H_]           = ar3;
  g_part[base + chs + 0*H_]     = az0;
  g_part[base + chs + 1*H_]     = az1;
  g_part[base + chs + 2*H_]     = az2;
  g_part[base + chs + 3*H_]     = az3;
  g_part[base + 2*chs + 0*H_]   = ai0;
  g_part[base + 2*chs + 1*H_]   = ai1;
  g_part[base + 2*chs + 2*H_]   = ai2;
  g_part[base + 2*chs + 3*H_]   = ai3;
  g_part[base + 3*chs + 0*H_]   = ah0;
  g_part[base + 3*chs + 1*H_]   = ah1;
  g_part[base + 3*chs + 2*H_]   = ah2;
  g_part[base + 3*chs + 3*H_]   = ah3;
}

// ---------------- per-step: pointwise GRU update ----------------
__global__ __launch_bounds__(256) void k_hupdate(int t) {
  int i = blockIdx.x * 256 + threadIdx.x;    // grid 256 -> 65536
  int jj = i & 1023;
  const size_t chs = (size_t)B_ * H_;
  double sr = 0.0, sz = 0.0, si = 0.0, sh = 0.0;
  #pragma unroll
  for (int ks = 0; ks < KS_; ++ks) {
    size_t base = (size_t)ks * 4 * chs + i;
    sr += g_part[base];
    sz += g_part[base + chs];
    si += g_part[base + 2 * chs];
    sh += g_part[base + 3 * chs];
  }
  sr += g_bih[jj] + g_bhh[jj];
  sz += g_bih[H_ + jj] + g_bhh[H_ + jj];
  si += g_bih[2 * H_ + jj];
  sh += g_bhh[2 * H_ + jj];
  double r = 1.0 / (1.0 + exp(-sr));
  double z = 1.0 / (1.0 + exp(-sz));
  double n = tanh(si + r * sh);
  double hold = g_h64[i];
  double hnew = (1.0 - z) * n + z * hold;
  g_h64[i] = hnew;
  g_hist[(size_t)t * chs + i] = (float)hnew;
}

// ---------------- per-step: logits (f64) + Bernoulli mask + next curr_in ----------------
// grid: (32 fc, 8 bg), block 256.  thread: fl = tid&15 (f), kg = tid>>4 (K-group of 16)
// Each thread: 8 independent accumulation chains (one per b), 64 k each -> LDS tree reduce.
__global__ __launch_bounds__(256) void k_logitmask(int t,
                                                   const float* __restrict__ u,
                                                   const float* __restrict__ x,
                                                   float* __restrict__ out) {
  const int tid = threadIdx.x;
  const int fl  = tid & 15;
  const int kg  = tid >> 4;           // 0..15
  const int f   = blockIdx.x * 16 + fl;
  const int b0  = blockIdx.y * 8;

  __shared__ double sh_h[8][130];     // staged h chunk [8b][128k], 8.3 KB
  __shared__ double red[16][16][9];   // [kg][fl][b] padded, 18 KB

  double acc[8];
  #pragma unroll
  for (int i = 0; i < 8; ++i) acc[i] = 0.0;

  #pragma unroll 1
  for (int c = 0; c < 8; ++c) {
    #pragma unroll
    for (int it = 0; it < 4; ++it) {
      int e  = it * 256 + tid;        // 0..1023
      int bb = e >> 7;                // 0..7
      int kk = e & 127;               // consecutive lanes -> consecutive k (coalesced)
      sh_h[bb][kk] = g_h64[(size_t)(b0 + bb) * H_ + c * 128 + kk];
    }
    __syncthreads();
    const float* wp = &g_WselTf[(size_t)(c * 128 + kg * 8) * F_ + f];
    #pragma unroll
    for (int ki = 0; ki < 8; ++ki) {
      double w = (double)wp[0];
      wp += F_;
      #pragma unroll
      for (int bb = 0; bb < 8; ++bb)
        acc[bb] = fma(sh_h[bb][kg * 8 + ki], w, acc[bb]);
    }
    __syncthreads();
  }

  #pragma unroll
  for (int bb = 0; bb < 8; ++bb) red[kg][fl][bb] = acc[bb];
  __syncthreads();

  bool wflag = false;
  if (tid < 128) {
    int fl2 = tid & 15, bb2 = tid >> 4;     // bb2 0..7
    double s = 0.0;
    #pragma unroll
    for (int kk = 0; kk < 16; ++kk) s += red[kk][fl2][bb2];
    int ff = blockIdx.x * 16 + fl2;
    int bb = b0 + bb2;
    double logit = s + g_bsel[ff];
    double sig = 1.0 / (1.0 + exp(-logit));
    int tp = t + 1;
    float uv = u[(size_t)tp * (B_ * F_) + (size_t)bb * F_ + ff];
    wflag = sig > (double)uv;
    out[(size_t)SEL_OFF + (size_t)tp * (B_ * F_) + (size_t)bb * F_ + ff] = wflag ? 1.0f : 0.0f;
    g_ci64[bb * F_ + ff] = wflag ? (double)x[(size_t)bb * (T_ * F_) + (size_t)tp * F_ + ff] : 0.0;
  }
  unsigned long long bal = __ballot(wflag);
  if (tid < 128 && (tid & 63) == 0) atomicAdd(&g_selcnt, (unsigned)__popcll(bal));
}

// ---------------- batched out-GEMM (f32): out[m][o] = hist[m][:] . W_out[o][:] + b_out ----------------
__global__ __launch_bounds__(256) void k_out(const float* __restrict__ Wo,
                                             const float* __restrict__ bo,
                                             float* __restrict__ out) {
  __shared__ float sA[32][68];
  __shared__ float sB[32][68];
  const int tid = threadIdx.x;
  const int to = tid & 15, tm = tid >> 4;
  const int m0 = blockIdx.y * 64, o0 = blockIdx.x * 64;
  float acc[4][4] = {{0.f}};
  for (int kt = 0; kt < 1024 / 32; ++kt) {
    #pragma unroll
    for (int it = 0; it < 8; ++it) {
      int e  = it * 256 + tid;   // 0..2047
      int rl = e >> 5;           // 0..63
      int kl = e & 31;
      sA[kl][rl] = g_hist[(size_t)(m0 + rl) * H_ + kt * 32 + kl];
      sB[kl][rl] = Wo[(size_t)(o0 + rl) * H_ + kt * 32 + kl];
    }
    __syncthreads();
    #pragma unroll
    for (int kl = 0; kl < 32; ++kl) {
      float a[4], bv[4];
      #pragma unroll
      for (int i = 0; i < 4; ++i) a[i] = sA[kl][tm * 4 + i];
      #pragma unroll
      for (int i = 0; i < 4; ++i) bv[i] = sB[kl][to * 4 + i];
      #pragma unroll
      for (int i = 0; i < 4; ++i)
        #pragma unroll
        for (int c = 0; c < 4; ++c)
          acc[i][c] = fmaf(a[i], bv[c], acc[i][c]);
    }
    __syncthreads();
  }
  #pragma unroll
  for (int i = 0; i < 4; ++i) {
    int m = m0 + tm * 4 + i;
    #pragma unroll
    for (int c = 0; c < 4; ++c) {
      int o = o0 + to * 4 + c;
      out[(size_t)m * O_ + o] = acc[i][c] + bo[o];
    }
  }
}

__global__ void k_finalize(float* __restrict__ out) {
  if (blockIdx.x == 0 && threadIdx.x == 0) out[NSEL_IX] = (float)g_selcnt;
}

// ---------------- launcher ----------------
extern "C" void kernel_launch(void* const* d_in, const int* in_sizes, int n_in,
                              void* d_out, int out_size, void* d_ws, size_t ws_size,
                              hipStream_t stream) {
  (void)in_sizes; (void)n_in; (void)out_size; (void)d_ws; (void)ws_size;
  const float* x     = (const float*)d_in[0];
  const float* u     = (const float*)d_in[1];
  const float* W_ih  = (const float*)d_in[2];
  const float* b_ih  = (const float*)d_in[3];
  const float* W_hh  = (const float*)d_in[4];
  const float* b_hh  = (const float*)d_in[5];
  const float* W_out = (const float*)d_in[6];
  const float* b_out = (const float*)d_in[7];
  const float* W_sel = (const float*)d_in[8];
  const float* b_sel = (const float*)d_in[9];
  float* out = (float*)d_out;

  k_prep_wihT <<<(F_ * G3_ + 255) / 256, 256, 0, stream>>>(W_ih);
  k_prep_whhT <<<(H_ * G3_ + 255) / 256, 256, 0, stream>>>(W_hh);
  k_prep_wselT<<<(H_ * F_ + 255) / 256, 256, 0, stream>>>(W_sel);
  k_prep_misc <<<256, 256, 0, stream>>>(x, b_ih, b_hh, b_sel, out);

  for (int t = 0; t < T_; ++t) {
    k_gates  <<<dim3(32, KS_), 512, 0, stream>>>();
    k_hupdate<<<256, 256, 0, stream>>>(t);
    if (t < T_ - 1)
      k_logitmask<<<dim3(32, 8), 256, 0, stream>>>(t, u, x, out);
  }

  k_out<<<dim3(8, 256), 256, 0, stream>>>(W_out, b_out, out);
  k_finalize<<<1, 1, 0, stream>>>(out);
}